// Round 9
// baseline (122.226 us; speedup 1.0000x reference)
//
#include <hip/hip_runtime.h>

// Causal dilated conv1d (dilation=64, K=2) + tanh*sigmoid gate via bf16 MFMA.
// v8 = v7 (3-bank ring, counted-vmcnt raw-barrier pipeline) + NON-TEMPORAL
// OUTPUT STORES.
//   System accounting: the harness poison-fill (256 MB at 6.4 TB/s) leaves
//   all of L3 dirty immediately before conv. Conv's ~107 MB of fetches +
//   write-allocates evict ~107 MB of dirty poison -> that writeback lands
//   INSIDE conv's window: 214 MB @ 6.29 TB/s = 34 us == measured 36.5 us.
//   Every v0-v7 variant was at this effective roofline (hence 8 rounds of
//   structural invariance). out is never re-read: nt stores (gfx950 'nt'
//   bit, no-allocate/streaming) stop evicting poison for the 66 MB write
//   stream -> up to ~10 us less in-window writeback. Loads stay cached
//   (L3/L2 serve ~43 MB of halo/re-read demand; FETCH 41 MB < 84 MB demand).
// Carried from v7:
//  - raw s_barrier + lgkmcnt(0) only (no vmcnt drain in the loop);
//    2-deep load pipeline (W0..W3 prologue, W4 at iter-0 tail).
//  - LDS swizzle S(rr)=(rr&7)^((rr>>3)&7) on write AND read (2-way max).
//  - 3 banks x 64 rows x 64 ci bf16 = 24 KB; chunk k reads windows k,k+1
//    (banks k%3,(k+1)%3), stages W(k+2); 1024 blocks = 4/CU, XCD swizzle.
//  - transposed-output MFMA (A=x,B=w) -> float4 stores; deferred epilogue.
// w split hi/lo (2 MFMA terms, fp32-grade w); x single RNE bf16.
// y[b,co,t] = sum_ci w[co][ci][0]*x[b][ci][t-64] + w[co][ci][1]*x[b][ci][t]

#define B_ 16
#define C_ 64
#define T_ 16384

typedef __attribute__((ext_vector_type(8))) short short8;
typedef __attribute__((ext_vector_type(4))) float f32x4;

union Frag { short8 s; unsigned u[4]; };

__device__ __forceinline__ unsigned bf16_rne(float f) {
    unsigned u = __float_as_uint(f);
    return (u + 0x7fffu + ((u >> 16) & 1u)) >> 16;
}

__device__ __forceinline__ unsigned pack_rne(float a, float b) {
    unsigned ua = __float_as_uint(a), ub = __float_as_uint(b);
    unsigned ra = ua + 0x7fffu + ((ua >> 16) & 1u);
    unsigned rb = ub + 0x7fffu + ((ub >> 16) & 1u);
    return (ra >> 16) | (rb & 0xffff0000u);
}

// Raw barrier: LDS visibility only — no vmcnt drain.
#define LBAR()                                                              \
    do {                                                                    \
        asm volatile("s_waitcnt lgkmcnt(0)" ::: "memory");                  \
        __builtin_amdgcn_s_barrier();                                       \
    } while (0)

// Gate + NT store for chunk KK (transposed D): lane (m,q) holds
// t = KK*64+16s+4q+r of out row co = wid*16+m.
// tanh(y)*sigmoid(y) = (1-u)/(1+u^2), u=e^-y.
#define EPILOGUE(A, KK)                                                     \
    _Pragma("unroll")                                                       \
    for (int s = 0; s < 4; ++s) {                                           \
        f32x4 o4;                                                           \
        _Pragma("unroll")                                                   \
        for (int r = 0; r < 4; ++r) {                                       \
            float y = fmaxf((A)[s][r], -30.f);                              \
            float u = __expf(-y);                                           \
            o4[r] = (1.f - u) *                                             \
                __builtin_amdgcn_rcpf(__builtin_fmaf(u, u, 1.f));           \
        }                                                                   \
        __builtin_nontemporal_store(                                        \
            o4, (f32x4*)(ob + (KK) * 64 + 16 * s + 4 * q));                 \
    }

// In-register transpose of 4 float4 (4 ci x 4 t) -> 4x 8-B LDS writes.
#define STAGE_WRITE(F, BANK)                                                \
    _Pragma("unroll")                                                       \
    for (int e = 0; e < 4; ++e) {                                           \
        const int rr = 4 * tq + e;                                          \
        const int sw = (rr & 7) ^ ((rr >> 3) & 7);                          \
        const int so = (BANK) * 4096 + rr * 64 +                            \
                       (((c4 >> 1) ^ sw) * 8) + ((c4 & 1) * 4);             \
        unsigned u0 = pack_rne(((const float*)&(F)[0])[e],                  \
                               ((const float*)&(F)[1])[e]);                 \
        unsigned u1 = pack_rne(((const float*)&(F)[2])[e],                  \
                               ((const float*)&(F)[3])[e]);                 \
        *(uint2*)(&xs[so]) = make_uint2(u0, u1);                            \
    }

__global__ __launch_bounds__(256, 4) void conv_gate_nt(
    const float* __restrict__ x,
    const float* __restrict__ w,
    float* __restrict__ out)
{
    __shared__ unsigned short xs[3 * 64 * 64];   // 3 banks * 8 KB = 24576 B

    const int tid = threadIdx.x;
    const int bid = blockIdx.x;
    // XCD-bijective swizzle (1024 wgs, 8 XCDs).
    const int wg  = (bid & 7) * 128 + (bid >> 3);
    const int b   = wg >> 6;          // batch
    const int seg = wg & 63;          // 256-t segment
    const int t0  = seg << 8;
    const float* xb = x + (size_t)b * C_ * T_;

    // staging task: thread owns ci quad 4*c4..+3, t quad 4*tq..+3
    const int c4 = tid >> 4;          // 0..15
    const int tq = tid & 15;          // 0..15
    const float* xgb = xb + (size_t)(4 * c4) * T_ + 4 * tq;

    // ---- prologue: issue wide loads for W0..W3 (16 dwordx4 in flight)
    float4 fa[4], fb[4], fv[2][4];
    if (seg > 0) {
        #pragma unroll
        for (int i = 0; i < 4; ++i)
            fa[i] = *(const float4*)(xgb + (size_t)i * T_ + (t0 - 64));
    } else {
        #pragma unroll
        for (int i = 0; i < 4; ++i) fa[i] = make_float4(0.f, 0.f, 0.f, 0.f);
    }
    #pragma unroll
    for (int i = 0; i < 4; ++i)
        fb[i] = *(const float4*)(xgb + (size_t)i * T_ + t0);
    #pragma unroll
    for (int i = 0; i < 4; ++i)
        fv[0][i] = *(const float4*)(xgb + (size_t)i * T_ + (t0 + 64));
    #pragma unroll
    for (int i = 0; i < 4; ++i)
        fv[1][i] = *(const float4*)(xgb + (size_t)i * T_ + (t0 + 128));

    // ---- per-wave w fragments, hi/lo RNE split (covers x load latency)
    const int lane = tid & 63;
    const int wid  = tid >> 6;
    const int m    = lane & 15;
    const int q    = lane >> 4;
    const int co   = wid * 16 + m;

    Frag wh[2][2], wl[2][2];   // [tap p][k-half h]
    #pragma unroll
    for (int h = 0; h < 2; ++h) {
        const float* wp = w + co * 128 + h * 64 + q * 16;
        float f[16];
        #pragma unroll
        for (int v4 = 0; v4 < 4; ++v4) {
            float4 t4 = *(const float4*)(wp + 4 * v4);
            f[4*v4+0] = t4.x; f[4*v4+1] = t4.y; f[4*v4+2] = t4.z; f[4*v4+3] = t4.w;
        }
        #pragma unroll
        for (int p = 0; p < 2; ++p) {
            #pragma unroll
            for (int d = 0; d < 4; ++d) {
                float e0 = f[2*(2*d)   + p];
                float e1 = f[2*(2*d+1) + p];
                unsigned h0 = bf16_rne(e0), h1 = bf16_rne(e1);
                float r0 = e0 - __uint_as_float(h0 << 16);
                float r1 = e1 - __uint_as_float(h1 << 16);
                wh[p][h].u[d] = h0 | (h1 << 16);
                wl[p][h].u[d] = bf16_rne(r0) | (bf16_rne(r1) << 16);
            }
        }
    }

    // ---- prologue: stage W0,W1 into banks 0,1 (auto-counted vmcnt waits)
    STAGE_WRITE(fa, 0)
    STAGE_WRITE(fb, 1)

    float* ob = out + ((size_t)b * C_ + wid * 16 + m) * T_ + t0;   // transposed row

    f32x4 acc2[2][4];

    LBAR();

    // ---- 4 chunks of 64 t; raw barriers, no vmcnt drain anywhere.
    #pragma unroll
    for (int k = 0; k < 4; ++k) {
        // (1) deferred epilogue of chunk k-1 (nt stores pipeline freely)
        if (k >= 1) { EPILOGUE(acc2[(k & 1) ^ 1], k - 1); }

        // (2) compute chunk k: windows k (tap0), k+1 (tap1) in banks k%3,(k+1)%3
        f32x4* acc = acc2[k & 1];
        #pragma unroll
        for (int s = 0; s < 4; ++s) acc[s] = (f32x4){0.f, 0.f, 0.f, 0.f};
        #pragma unroll
        for (int u = 0; u < 8; ++u) {
            const int wnd  = k + (u >> 2);                 // compile-time
            const int rr_r = 16 * (u & 3) + m;             // row in window
            const int sw_r = (rr_r & 7) ^ ((rr_r >> 3) & 7);
            const int rbase = (wnd % 3) * 4096 + rr_r * 64;
            Frag f0, f1;
            f0.s = *(const short8*)(&xs[rbase + ((q ^ sw_r) * 8)]);        // ci 8q..
            f1.s = *(const short8*)(&xs[rbase + (((4 + q) ^ sw_r) * 8)]);  // ci 32+8q..
            if (u < 4) {
                acc[u] = __builtin_amdgcn_mfma_f32_16x16x32_bf16(f0.s, wh[0][0].s, acc[u], 0, 0, 0);
                acc[u] = __builtin_amdgcn_mfma_f32_16x16x32_bf16(f0.s, wl[0][0].s, acc[u], 0, 0, 0);
                acc[u] = __builtin_amdgcn_mfma_f32_16x16x32_bf16(f1.s, wh[0][1].s, acc[u], 0, 0, 0);
                acc[u] = __builtin_amdgcn_mfma_f32_16x16x32_bf16(f1.s, wl[0][1].s, acc[u], 0, 0, 0);
            } else {
                const int s2 = u - 4;
                acc[s2] = __builtin_amdgcn_mfma_f32_16x16x32_bf16(f0.s, wh[1][0].s, acc[s2], 0, 0, 0);
                acc[s2] = __builtin_amdgcn_mfma_f32_16x16x32_bf16(f0.s, wl[1][0].s, acc[s2], 0, 0, 0);
                acc[s2] = __builtin_amdgcn_mfma_f32_16x16x32_bf16(f1.s, wh[1][1].s, acc[s2], 0, 0, 0);
                acc[s2] = __builtin_amdgcn_mfma_f32_16x16x32_bf16(f1.s, wl[1][1].s, acc[s2], 0, 0, 0);
            }
        }

        // (3) stage W(k+2) from regs loaded >=1 iteration ago into bank (k+2)%3
        if (k <= 2) { STAGE_WRITE(fv[k & 1], (k + 2) % 3) }

        // (3b) issue W4 loads into the buffer just packed (2-iteration cover)
        if (k == 0) {
            #pragma unroll
            for (int i = 0; i < 4; ++i)
                fv[0][i] = *(const float4*)(xgb + (size_t)i * T_ + (t0 + 192));
        }

        // (4) raw barrier: LDS writes visible, VMEM queue stays full
        if (k < 3) LBAR();
    }

    EPILOGUE(acc2[1], 3);
}

extern "C" void kernel_launch(void* const* d_in, const int* in_sizes, int n_in,
                              void* d_out, int out_size, void* d_ws, size_t ws_size,
                              hipStream_t stream) {
    const float* x = (const float*)d_in[0];
    const float* w = (const float*)d_in[1];
    float* out = (float*)d_out;
    conv_gate_nt<<<dim3(1024), dim3(256), 0, stream>>>(x, w, out);
}